// Round 4
// baseline (5393.494 us; speedup 1.0000x reference)
//
#include <hip/hip_runtime.h>

// VoxelProposalLayer fused deformable-attention proposal kernel.
// Round 4: EXACT-F32 bisect build — no MFMA, no bf16 anywhere in the query
// path. Both GEMMs are register-blocked f32 dot products (q row in VGPRs,
// transposed W from L2). Everything else identical to round 3.

#define V_TOT 262144
#define OAS 292   // s_oa row stride (floats)

// ---------------- mask kernels ----------------
__global__ void maskzero_kernel(unsigned int* pm) {
  pm[blockIdx.x * 512 + threadIdx.x] = 0u;   // 65536 words = 262144 bytes
}

__global__ void scatter_kernel(const int* __restrict__ vp, unsigned char* __restrict__ pm) {
  int v = blockIdx.x * 512 + threadIdx.x;
  int x = vp[v * 3 + 0], y = vp[v * 3 + 1], z = vp[v * 3 + 2];
  if (x >= 0 && x < 128 && y >= 0 && y < 128 && z >= 0 && z < 16)
    pm[x * 2048 + y * 16 + z] = 1;
}

// ---------------- value projection: vp[s][c] = value[s]@Wv + bv ----------------
__global__ void vproj_kernel(const float* __restrict__ f0, const float* __restrict__ f1,
                             const float* __restrict__ f2, const float* __restrict__ Wv,
                             const float* __restrict__ bv, float* __restrict__ vp) {
  __shared__ float lds[128][17];
  int t = threadIdx.x;
  int s0 = blockIdx.x * 16;
  const float* f; int hw, sl0;
  if (s0 < 12288)      { f = f0; hw = 12288; sl0 = s0; }
  else if (s0 < 15360) { f = f1; hw = 3072;  sl0 = s0 - 12288; }
  else                 { f = f2; hw = 768;   sl0 = s0 - 15360; }
  for (int u = 0; u < 8; ++u) {
    int idx = u * 256 + t;
    int k = idx >> 4, si = idx & 15;
    lds[k][si] = f[(size_t)k * hw + sl0 + si];
  }
  __syncthreads();
  for (int u = 0; u < 8; ++u) {
    int idx = u * 256 + t;
    int c = idx & 127, sr = idx >> 7;
    float acc = bv[c];
    #pragma unroll 8
    for (int k = 0; k < 128; ++k) acc += lds[k][sr] * Wv[k * 128 + c];
    vp[(size_t)(s0 + sr) * 128 + c] = acc;
  }
}

// ---------------- W transpose: WtOA[j][k], WtOut[j][k] (f32) ----------------
__global__ void wtrans_kernel(const float* __restrict__ Woff, const float* __restrict__ Wattn,
                              const float* __restrict__ Wout,
                              float* __restrict__ WtOA, float* __restrict__ WtOut) {
  int t = blockIdx.x * 512 + threadIdx.x;     // 72*512 = 36864
  if (t < 36864) {
    int j = t >> 7, k = t & 127;
    WtOA[t] = (j < 192) ? Woff[k * 192 + j] : Wattn[k * 96 + (j - 192)];
  }
  if (t < 16384) {
    int j = t >> 7, k = t & 127;
    WtOut[t] = Wout[k * 128 + j];
  }
}

// ---------------- main fused kernel ----------------
__global__ __launch_bounds__(512) void main_kernel(
    const float* __restrict__ embed, const float* __restrict__ pos,
    const float* __restrict__ refp, const float* __restrict__ vproj,
    const float* __restrict__ WtOA, const float* __restrict__ WtOut,
    const float* __restrict__ boff, const float* __restrict__ battn,
    const float* __restrict__ bout, const float* __restrict__ lng, const float* __restrict__ lnb,
    const unsigned char* __restrict__ ptsmask, const unsigned char* __restrict__ fovmask,
    float* __restrict__ out) {
  __shared__ __align__(16) float s_oa[32 * OAS];
  __shared__ __align__(16) float s_q[32][132];   // q rows; reused as sampled-acc rows in P4/P5
  __shared__ float s_reff[64];
  __shared__ int s_flag[32];
  __shared__ float s_boff[192], s_battn[96], s_bout[128], s_lng[128], s_lnb[128];
  __shared__ int s_fovint;

  int t = threadIdx.x;
  int v0 = blockIdx.x * 32;

  // ---- P0: loads; q = embed+pos (f32) ----
  if (t == 0) {
    const unsigned int* fw = (const unsigned int*)fovmask;
    int i32mode = 1;
    for (int i = 0; i < 8; ++i) i32mode &= (fw[i] <= 1u) ? 1 : 0;
    s_fovint = i32mode;
  }
  {
    const float4* e4 = (const float4*)(embed + (size_t)v0 * 128);
    const float4* p4 = (const float4*)(pos + (size_t)v0 * 128);
    #pragma unroll
    for (int r = 0; r < 2; ++r) {
      int fi = r * 512 + t;               // 0..1023 float4s (32 rows x 32 f4)
      float4 ev = e4[fi], pv = p4[fi];
      int i = fi >> 5, c = (fi & 31) * 4;
      float4 qv;
      qv.x = ev.x + pv.x; qv.y = ev.y + pv.y; qv.z = ev.z + pv.z; qv.w = ev.w + pv.w;
      *(float4*)&s_q[i][c] = qv;
    }
  }
  if (t < 64)  s_reff[t]  = refp[(size_t)v0 * 2 + t];
  if (t < 192) s_boff[t]  = boff[t];
  if (t < 96)  s_battn[t] = battn[t];
  if (t < 128) { s_bout[t] = bout[t]; s_lng[t] = lng[t]; s_lnb[t] = lnb[t]; }
  __syncthreads();

  // ---- P1: q @ [Woff|Wattn]  (M=32, N=288, K=128), exact f32 ----
  {
    int jg = t >> 5, m = t & 31;
    float4 qreg[32];
    #pragma unroll
    for (int k = 0; k < 32; ++k) qreg[k] = *(const float4*)&s_q[m][k * 4];
    #pragma unroll 1
    for (int jj = 0; jj < 18; ++jj) {
      int j = jg + jj * 16;               // 0..287
      const float4* wrow = (const float4*)&WtOA[j * 128];
      float acc = 0.f;
      #pragma unroll
      for (int k = 0; k < 32; ++k) {
        float4 w4 = wrow[k];
        acc += qreg[k].x * w4.x + qreg[k].y * w4.y + qreg[k].z * w4.z + qreg[k].w * w4.w;
      }
      s_oa[m * OAS + j] = acc;
    }
  }
  __syncthreads();

  // ---- P2: flags + softmax over 12 (l,p) per (query,head) ----
  if (t < 32) {
    int v = v0 + t;
    int pm = ptsmask[v];
    int fv = s_fovint ? ((const int*)fovmask)[v] : (int)fovmask[v];
    s_flag[t] = pm ? (fv ? 2 : 1) : 0;
  }
  if (t < 256) {
    int i = t >> 3, h = t & 7;
    float* p = &s_oa[i * OAS + 192 + h * 12];
    const float* bb = &s_battn[h * 12];
    float l[12];
    float m = -1e30f;
    #pragma unroll
    for (int j = 0; j < 12; ++j) { l[j] = p[j] + bb[j]; m = fmaxf(m, l[j]); }
    float sum = 0.f;
    #pragma unroll
    for (int j = 0; j < 12; ++j) { l[j] = expf(l[j] - m); sum += l[j]; }
    float inv = 1.0f / sum;
    #pragma unroll
    for (int j = 0; j < 12; ++j) p[j] = l[j] * inv;
  }
  __syncthreads();

  // ---- P3: rewrite rows in place as (locx,locy,aw) per (h,l,p): 96*3 = 288 ----
  {
    const float invWn[3] = {1.f / 192.f, 1.f / 96.f, 1.f / 48.f};
    const float invHn[3] = {1.f / 64.f, 1.f / 32.f, 1.f / 16.f};
    float st[6][3];
    #pragma unroll
    for (int u = 0; u < 6; ++u) {
      int task = u * 512 + t;                 // 3072 tasks
      int i = task / 96, s = task % 96;
      int h = s / 12, lp = s % 12, l = lp >> 2, p = lp & 3;
      int oidx = ((h * 3 + l) * 4 + p) * 2;
      float ox = s_oa[i * OAS + oidx] + s_boff[oidx];
      float oy = s_oa[i * OAS + oidx + 1] + s_boff[oidx + 1];
      float aw = s_oa[i * OAS + 192 + h * 12 + lp];
      st[u][0] = s_reff[i * 2] + ox * invWn[l];
      st[u][1] = s_reff[i * 2 + 1] + oy * invHn[l];
      st[u][2] = aw;
    }
    __syncthreads();
    #pragma unroll
    for (int u = 0; u < 6; ++u) {
      int task = u * 512 + t;
      int i = task / 96, s = task % 96;
      float* d = &s_oa[i * OAS + s * 3];
      d[0] = st[u][0]; d[1] = st[u][1]; d[2] = st[u][2];
    }
  }
  __syncthreads();

  // ---- P4: bilinear sampling, active queries only; acc -> s_q rows (f32) ----
  {
    int qsub = t >> 7;                 // 0..3 (wave-uniform)
    int cch = t & 127, h = cch >> 4, dh = cch & 15;
    #pragma unroll 1
    for (int g = 0; g < 8; ++g) {
      int i = g * 4 + qsub;
      if (s_flag[i] == 2) {
        float acc = 0.f;
        #pragma unroll
        for (int lp = 0; lp < 12; ++lp) {
          const int Wl = (lp < 4) ? 192 : ((lp < 8) ? 96 : 48);
          const int Hl = (lp < 4) ? 64 : ((lp < 8) ? 32 : 16);
          const int Bl = (lp < 4) ? 0 : ((lp < 8) ? 12288 : 15360);
          const float* pd = &s_oa[i * OAS + (h * 12 + lp) * 3];
          float lx = pd[0], ly = pd[1], aw = pd[2];
          float x = lx * (float)Wl - 0.5f, y = ly * (float)Hl - 0.5f;
          float xf = floorf(x), yf = floorf(y);
          float wx = x - xf, wy = y - yf;
          int x0 = (int)xf, y0 = (int)yf;
          const float* vb = vproj + (size_t)Bl * 128 + h * 16 + dh;
          float sv = 0.f;
          #pragma unroll
          for (int dy2 = 0; dy2 < 2; ++dy2) {
            #pragma unroll
            for (int dx2 = 0; dx2 < 2; ++dx2) {
              int ix = x0 + dx2, iy = y0 + dy2;
              if (ix >= 0 && ix < Wl && iy >= 0 && iy < Hl) {
                float w = (dx2 ? wx : 1.f - wx) * (dy2 ? wy : 1.f - wy);
                sv += w * vb[(size_t)(iy * Wl + ix) * 128];
              }
            }
          }
          acc += aw * sv;
        }
        s_q[i][cch] = acc;
      }
    }
  }
  __syncthreads();

  // ---- P5: acc @ Wout + identity(global) + bout, exact f32 ----
  {
    int jg = t >> 5, m = t & 31;
    float4 areg[32];
    #pragma unroll
    for (int k = 0; k < 32; ++k) areg[k] = *(const float4*)&s_q[m][k * 4];
    #pragma unroll 1
    for (int jj = 0; jj < 8; ++jj) {
      int j = jg + jj * 16;               // 0..127
      const float4* wrow = (const float4*)&WtOut[j * 128];
      float acc = 0.f;
      #pragma unroll
      for (int k = 0; k < 32; ++k) {
        float4 w4 = wrow[k];
        acc += areg[k].x * w4.x + areg[k].y * w4.y + areg[k].z * w4.z + areg[k].w * w4.w;
      }
      float idv = embed[(size_t)(v0 + m) * 128 + j];
      s_oa[m * OAS + j] = acc + idv + s_bout[j];
    }
  }
  __syncthreads();

  // ---- P6: LayerNorm rows ----
  {
    int i = t >> 4, j = t & 15;
    float* rowp = &s_oa[i * OAS];
    float4 a = *(float4*)&rowp[j * 8];
    float4 b = *(float4*)&rowp[j * 8 + 4];
    float vals[8] = {a.x, a.y, a.z, a.w, b.x, b.y, b.z, b.w};
    float sum = 0.f, sq = 0.f;
    #pragma unroll
    for (int e = 0; e < 8; ++e) { sum += vals[e]; sq += vals[e] * vals[e]; }
    #pragma unroll
    for (int m = 1; m < 16; m <<= 1) {
      sum += __shfl_xor(sum, m);
      sq  += __shfl_xor(sq, m);
    }
    float mean = sum * (1.f / 128.f);
    float var = sq * (1.f / 128.f) - mean * mean;
    float rs = rsqrtf(var + 1e-5f);
    #pragma unroll
    for (int e = 0; e < 8; ++e) {
      int c = j * 8 + e;
      rowp[c] = (vals[e] - mean) * rs * s_lng[c] + s_lnb[c];
    }
  }
  __syncthreads();

  // ---- P7: masked transpose write ----
  #pragma unroll
  for (int rep = 0; rep < 8; ++rep) {
    int idx = rep * 512 + t;
    int c = idx >> 5, i = idx & 31;
    int fl = s_flag[i];
    float val;
    if (fl == 2)      val = s_oa[i * OAS + c];
    else if (fl == 1) val = 0.f;
    else              val = embed[(size_t)(v0 + i) * 128 + c];
    out[(size_t)c * V_TOT + (v0 + i)] = val;
  }
}

extern "C" void kernel_launch(void* const* d_in, const int* in_sizes, int n_in,
                              void* d_out, int out_size, void* d_ws, size_t ws_size,
                              hipStream_t stream) {
  const float* embed = (const float*)d_in[0];
  const float* pos   = (const float*)d_in[1];
  const float* refp  = (const float*)d_in[2];
  const float* f0    = (const float*)d_in[3];
  const float* f1    = (const float*)d_in[4];
  const float* f2    = (const float*)d_in[5];
  const float* Wv    = (const float*)d_in[6];
  const float* bv    = (const float*)d_in[7];
  const float* Woff  = (const float*)d_in[8];
  const float* boff  = (const float*)d_in[9];
  const float* Wattn = (const float*)d_in[10];
  const float* battn = (const float*)d_in[11];
  const float* Wout  = (const float*)d_in[12];
  const float* bout  = (const float*)d_in[13];
  const float* lng   = (const float*)d_in[14];
  const float* lnb   = (const float*)d_in[15];
  const int*   volp  = (const int*)d_in[16];
  const unsigned char* fov = (const unsigned char*)d_in[17];
  float* out = (float*)d_out;

  char* ws = (char*)d_ws;
  float* vproj = (float*)ws;                                 // 8,257,536 B
  size_t off1 = 8257536;
  unsigned char* pmask = (unsigned char*)(ws + off1);        // 262,144 B
  size_t off2 = off1 + 262144;
  float* WtOA  = (float*)(ws + off2);                        // 147,456 B
  float* WtOut = (float*)(ws + off2 + 147456);               // 65,536 B

  maskzero_kernel<<<128, 512, 0, stream>>>((unsigned int*)pmask);
  scatter_kernel<<<512, 512, 0, stream>>>(volp, pmask);
  vproj_kernel<<<1008, 256, 0, stream>>>(f0, f1, f2, Wv, bv, vproj);
  wtrans_kernel<<<72, 512, 0, stream>>>(Woff, Wattn, Wout, WtOA, WtOut);
  main_kernel<<<8192, 512, 0, stream>>>(embed, pos, refp, vproj,
                                        WtOA, WtOut,
                                        boff, battn, bout, lng, lnb,
                                        pmask, fov, out);
}

// Round 5
// 1407.999 us; speedup vs baseline: 3.8306x; 3.8306x over previous
//
#include <hip/hip_runtime.h>

// VoxelProposalLayer — round 5: compaction + runtime-verified MFMA (f32 fallback)
// Kernels: zero -> scatter -> probe -> vproj(bf16) -> wfrag -> flags/compact/passthrough -> attn

typedef __attribute__((ext_vector_type(8))) short short8v;
typedef __attribute__((ext_vector_type(4))) float f32x4;

#define V_TOT 262144
#define OAS 292
#define NBLK_ATTN 2048

__device__ __forceinline__ unsigned short f2bf(float f) {
  unsigned int u = __float_as_uint(f);
  u += 0x7fffu + ((u >> 16) & 1u);   // RNE
  return (unsigned short)(u >> 16);
}
__device__ __forceinline__ float bf2f(unsigned short h) {
  return __uint_as_float(((unsigned int)h) << 16);
}

// ---------------- zero: pmask + counter ----------------
__global__ void zero_kernel(unsigned int* pm, unsigned int* counter) {
  pm[blockIdx.x * 512 + threadIdx.x] = 0u;   // 65536 words
  if (blockIdx.x == 0 && threadIdx.x == 0) *counter = 0u;
}

__global__ void scatter_kernel(const int* __restrict__ vp, unsigned char* __restrict__ pm) {
  int v = blockIdx.x * 512 + threadIdx.x;
  int x = vp[v * 3 + 0], y = vp[v * 3 + 1], z = vp[v * 3 + 2];
  if (x >= 0 && x < 128 && y >= 0 && y < 128 && z >= 0 && z < 16)
    pm[x * 2048 + y * 16 + z] = 1;
}

// ---------------- probe: MFMA layout hypothesis + fov dtype ----------------
__global__ void probe_kernel(const unsigned char* __restrict__ fov, int* __restrict__ pflags) {
  int l = threadIdx.x;              // 64
  int n = l & 15, kb = (l >> 4) * 8;
  short8v a, b0, b17;
  #pragma unroll
  for (int e = 0; e < 8; ++e) {
    a[e]   = (short)f2bf((float)n);                              // A[m][k] = m (m=l&15)
    b0[e]  = (kb + e == 0)  ? (short)f2bf((float)(n + 1)) : (short)0;  // B[0][n]=n+1
    b17[e] = (kb + e == 17) ? (short)f2bf((float)(n + 3)) : (short)0;  // B[17][n]=n+3
  }
  f32x4 z = {0.f, 0.f, 0.f, 0.f};
  f32x4 d0  = __builtin_amdgcn_mfma_f32_16x16x32_bf16(a, b0,  z, 0, 0, 0);
  f32x4 d17 = __builtin_amdgcn_mfma_f32_16x16x32_bf16(a, b17, z, 0, 0, 0);
  bool ok0 = true, ok1 = true;
  #pragma unroll
  for (int r = 0; r < 4; ++r) {
    float rA = (float)((l >> 4) * 4 + r);   // H0 row
    float cA = (float)(l & 15);             // H0 col
    ok0 = ok0 && (d0[r] == rA * (cA + 1.f)) && (d17[r] == rA * (cA + 3.f));
    ok1 = ok1 && (d0[r] == cA * (rA + 1.f)) && (d17[r] == cA * (rA + 3.f));
  }
  bool all0 = __all(ok0), all1 = __all(ok1);
  if (l == 0) {
    pflags[0] = all0 ? 0 : (all1 ? 1 : 2);
    const unsigned int* fw = (const unsigned int*)fov;
    int i32mode = 1;
    for (int i = 0; i < 8; ++i) i32mode &= (fw[i] <= 1u) ? 1 : 0;
    pflags[1] = i32mode;
  }
}

// ---------------- vproj: vp_bf[s][c] = bf16(value[s]@Wv + bv) ----------------
__global__ void vproj_kernel(const float* __restrict__ f0, const float* __restrict__ f1,
                             const float* __restrict__ f2, const float* __restrict__ Wv,
                             const float* __restrict__ bv, unsigned short* __restrict__ vp) {
  __shared__ __align__(16) float lds[128][20];
  int t = threadIdx.x;            // 256
  int s0 = blockIdx.x * 16;
  const float* f; int hw, sl0;
  if (s0 < 12288)      { f = f0; hw = 12288; sl0 = s0; }
  else if (s0 < 15360) { f = f1; hw = 3072;  sl0 = s0 - 12288; }
  else                 { f = f2; hw = 768;   sl0 = s0 - 15360; }
  for (int u = 0; u < 8; ++u) {
    int idx = u * 256 + t;
    int k = idx >> 4, si = idx & 15;
    lds[k][si] = f[(size_t)k * hw + sl0 + si];
  }
  __syncthreads();
  {
    int c = t & 127, half = t >> 7;   // sites half*8 .. half*8+7
    int base = half * 8;
    f32x4 acc0 = {0.f,0.f,0.f,0.f}, acc1 = {0.f,0.f,0.f,0.f};
    #pragma unroll 4
    for (int k = 0; k < 128; ++k) {
      float w = Wv[k * 128 + c];
      f32x4 l0 = *(const f32x4*)&lds[k][base];
      f32x4 l1 = *(const f32x4*)&lds[k][base + 4];
      acc0 += l0 * w;
      acc1 += l1 * w;
    }
    float b = bv[c];
    #pragma unroll
    for (int j = 0; j < 4; ++j) {
      vp[(size_t)(s0 + base + j)     * 128 + c] = f2bf(acc0[j] + b);
      vp[(size_t)(s0 + base + 4 + j) * 128 + c] = f2bf(acc1[j] + b);
    }
  }
}

// ---------------- wfrag: hi/lo B-fragments + f32 transposed copies ----------
__global__ void wfrag_kernel(const float* __restrict__ Woff, const float* __restrict__ Wattn,
                             const float* __restrict__ Wout,
                             unsigned short* __restrict__ foa_hi, unsigned short* __restrict__ foa_lo,
                             unsigned short* __restrict__ fout_hi, unsigned short* __restrict__ fout_lo,
                             float* __restrict__ WtOA, float* __restrict__ WtOut) {
  int t = blockIdx.x * 512 + threadIdx.x;     // 40960
  int e = t & 7, lane = (t >> 3) & 63, kc = (t >> 9) & 3, nt = t >> 11;
  int k = kc * 32 + (lane >> 4) * 8 + e;
  int j = nt * 16 + (lane & 15);
  float v = (j < 192) ? Woff[k * 192 + j] : ((j < 288) ? Wattn[k * 96 + (j - 192)] : 0.f);
  unsigned short hi = f2bf(v);
  foa_hi[t] = hi;
  foa_lo[t] = f2bf(v - bf2f(hi));
  if (t < 16384) {
    float w = Wout[k * 128 + j];
    unsigned short whi = f2bf(w);
    fout_hi[t] = whi;
    fout_lo[t] = f2bf(w - bf2f(whi));
  }
  if (t < 36864) {
    int jj = t >> 7, kk = t & 127;
    WtOA[t] = (jj < 192) ? Woff[kk * 192 + jj] : Wattn[kk * 96 + (jj - 192)];
  }
  if (t < 16384) {
    int jj = t >> 7, kk = t & 127;
    WtOut[t] = Wout[kk * 128 + jj];
  }
}

// ---------------- flags + compaction + passthrough output ----------------
__global__ __launch_bounds__(256) void flags_kernel(
    const float* __restrict__ embed, const unsigned char* __restrict__ pmask,
    const unsigned char* __restrict__ fovmask, const int* __restrict__ pflags,
    unsigned int* __restrict__ counter, int* __restrict__ act,
    float* __restrict__ out) {
  __shared__ __align__(16) float tr[64][133];
  __shared__ int s_fl[64];
  __shared__ int s_fovint;
  int t = threadIdx.x;
  int v0 = blockIdx.x * 64;
  if (t == 0) s_fovint = pflags[1];
  // stage embed rows (coalesced)
  {
    const float4* e4 = (const float4*)(embed + (size_t)v0 * 128);
    #pragma unroll
    for (int r = 0; r < 8; ++r) {
      int fi = r * 256 + t;             // 2048 f4
      int i = fi >> 5, c4 = fi & 31;
      float4 ev = e4[fi];
      *(float4*)&tr[i][c4 * 4] = ev;
    }
  }
  __syncthreads();
  if (t < 64) {
    int v = v0 + t;
    int pm = pmask[v];
    int fv = s_fovint ? ((const int*)fovmask)[v] : (int)fovmask[v];
    int fl = pm ? (fv ? 2 : 1) : 0;
    s_fl[t] = fl;
    unsigned long long msk = __ballot(fl == 2);
    int cnt = __popcll(msk);
    int base = 0;
    if (t == 0 && cnt) base = atomicAdd(counter, (unsigned int)cnt);
    base = __shfl(base, 0);
    if (fl == 2) {
      int pos = __popcll(msk & ((1ull << t) - 1ull));
      act[base + pos] = v;
    }
  }
  __syncthreads();
  // passthrough write: flag0 -> embed, else 0 (attn overwrites flag2)
  float4* out4 = (float4*)out;
  #pragma unroll
  for (int it = 0; it < 8; ++it) {
    int task = it * 256 + t;            // 2048 = 128c x 16 f4
    int c = task >> 4, q = task & 15;
    float4 o;
    #pragma unroll
    for (int j = 0; j < 4; ++j) {
      int vi = q * 4 + j;
      o[j] = (s_fl[vi] == 0) ? tr[vi][c] : 0.f;
    }
    out4[(size_t)c * (V_TOT / 4) + (v0 >> 2) + q] = o;
  }
}

// ---------------- main attention kernel (compacted, persistent) -------------
__global__ __launch_bounds__(512) void attn_kernel(
    const float* __restrict__ embed, const float* __restrict__ pos,
    const float* __restrict__ refp, const unsigned short* __restrict__ vproj,
    const unsigned short* __restrict__ WfragOAh, const unsigned short* __restrict__ WfragOAl,
    const unsigned short* __restrict__ WfragOuth, const unsigned short* __restrict__ WfragOutl,
    const float* __restrict__ WtOA, const float* __restrict__ WtOut,
    const float* __restrict__ boff, const float* __restrict__ battn,
    const float* __restrict__ bout, const float* __restrict__ lng, const float* __restrict__ lnb,
    const int* __restrict__ act, const unsigned int* __restrict__ counter,
    const int* __restrict__ pflags,
    float* __restrict__ out) {
  __shared__ __align__(16) float s_oa[32 * OAS];
  __shared__ __align__(16) unsigned short s_qhi[32 * 128];
  __shared__ __align__(16) unsigned short s_qlo[32 * 128];
  __shared__ int s_vidx[32];
  __shared__ float s_reff[64];
  __shared__ float s_boff[192], s_battn[96], s_bout[128], s_lng[128], s_lnb[128];
  __shared__ int s_meta[3];   // count, mflag, ntiles

  int t = threadIdx.x;
  int wid = t >> 6, lane = t & 63;

  if (t == 0) {
    int cnt = (int)*counter;
    s_meta[0] = cnt;
    s_meta[1] = pflags[0];
    s_meta[2] = (cnt + 31) >> 5;
  }
  if (t < 192) s_boff[t]  = boff[t];
  if (t < 96)  s_battn[t] = battn[t];
  if (t < 128) { s_bout[t] = bout[t]; s_lng[t] = lng[t]; s_lnb[t] = lnb[t]; }
  __syncthreads();
  int count = s_meta[0], mflag = s_meta[1], ntiles = s_meta[2];

  for (int tile = blockIdx.x; tile < ntiles; tile += NBLK_ATTN) {
    int q0 = tile * 32;
    // ---- P0 ----
    if (t < 32) s_vidx[t] = (q0 + t < count) ? act[q0 + t] : -1;
    if (t < 64) {
      int i = t >> 1, comp = t & 1;
      int idx = q0 + i;
      int vid = (idx < count) ? act[idx] : -1;
      s_reff[t] = (vid >= 0) ? refp[(size_t)vid * 2 + comp] : 0.f;
    }
    {
      #pragma unroll
      for (int r = 0; r < 2; ++r) {
        int fi = r * 512 + t;               // 1024 f4 (32 rows x 32)
        int i = fi >> 5, c4 = fi & 31;
        int idx = q0 + i;
        int vid = (idx < count) ? act[idx] : -1;
        ushort4 hk = {0,0,0,0}, lk = {0,0,0,0};
        if (vid >= 0) {
          float4 ev = *(const float4*)(embed + (size_t)vid * 128 + c4 * 4);
          float4 pv = *(const float4*)(pos   + (size_t)vid * 128 + c4 * 4);
          float q_0 = ev.x + pv.x, q_1 = ev.y + pv.y, q_2 = ev.z + pv.z, q_3 = ev.w + pv.w;
          hk.x = f2bf(q_0); lk.x = f2bf(q_0 - bf2f(hk.x));
          hk.y = f2bf(q_1); lk.y = f2bf(q_1 - bf2f(hk.y));
          hk.z = f2bf(q_2); lk.z = f2bf(q_2 - bf2f(hk.z));
          hk.w = f2bf(q_3); lk.w = f2bf(q_3 - bf2f(hk.w));
        }
        int c = c4 * 4;
        int idxl = i * 128 + (((c >> 3) ^ (i & 7)) << 3) + (c & 7);
        *(ushort4*)&s_qhi[idxl] = hk;
        *(ushort4*)&s_qlo[idxl] = lk;
      }
    }
    __syncthreads();

    // ---- P1: q @ [Woff|Wattn] ----
    if (mflag < 2) {
      int mrow = (wid & 1) * 16;
      int ntb = (wid >> 1) * 5;
      f32x4 acc[5];
      #pragma unroll
      for (int r = 0; r < 5; ++r) acc[r] = (f32x4){0.f,0.f,0.f,0.f};
      int arow = mrow + (lane & 15);
      int asub = lane >> 4;
      #pragma unroll
      for (int kc = 0; kc < 4; ++kc) {
        int slot = kc * 4 + asub;
        int aidx = arow * 128 + ((slot ^ (arow & 7)) << 3);
        short8v ah = *(const short8v*)&s_qhi[aidx];
        short8v al = *(const short8v*)&s_qlo[aidx];
        #pragma unroll
        for (int r = 0; r < 5; ++r) {
          size_t bi = (size_t)(((ntb + r) * 4 + kc) * 64 + lane) * 8;
          short8v bh = *(const short8v*)&WfragOAh[bi];
          short8v bl = *(const short8v*)&WfragOAl[bi];
          acc[r] = __builtin_amdgcn_mfma_f32_16x16x32_bf16(ah, bh, acc[r], 0, 0, 0);
          acc[r] = __builtin_amdgcn_mfma_f32_16x16x32_bf16(al, bh, acc[r], 0, 0, 0);
          acc[r] = __builtin_amdgcn_mfma_f32_16x16x32_bf16(ah, bl, acc[r], 0, 0, 0);
        }
      }
      #pragma unroll
      for (int r = 0; r < 5; ++r) {
        #pragma unroll
        for (int e = 0; e < 4; ++e) {
          int rr = (mflag == 0) ? ((lane >> 4) * 4 + e) : (lane & 15);
          int cc = (mflag == 0) ? (lane & 15) : ((lane >> 4) * 4 + e);
          int col = (ntb + r) * 16 + cc;
          if (col < 288) s_oa[(mrow + rr) * OAS + col] = acc[r][e];
        }
      }
    } else {
      // f32 fallback (verified round-4 path; q = hi+lo from LDS)
      int jg = t >> 5, m = t & 31;
      #pragma unroll 1
      for (int jj = 0; jj < 18; ++jj) {
        int j = jg + jj * 16;
        float acc = 0.f;
        #pragma unroll
        for (int slot = 0; slot < 16; ++slot) {
          int aidx = m * 128 + ((slot ^ (m & 7)) << 3);
          const unsigned short* hp = &s_qhi[aidx];
          const unsigned short* lp2 = &s_qlo[aidx];
          const float* wr = &WtOA[j * 128 + slot * 8];
          #pragma unroll
          for (int e2 = 0; e2 < 8; ++e2)
            acc += (bf2f(hp[e2]) + bf2f(lp2[e2])) * wr[e2];
        }
        s_oa[m * OAS + j] = acc;
      }
    }
    __syncthreads();

    // ---- P2: softmax over 12 per (query,head) ----
    if (t < 256) {
      int i = t >> 3, h = t & 7;
      float* p = &s_oa[i * OAS + 192 + h * 12];
      const float* bb = &s_battn[h * 12];
      float l[12];
      float m = -1e30f;
      #pragma unroll
      for (int j = 0; j < 12; ++j) { l[j] = p[j] + bb[j]; m = fmaxf(m, l[j]); }
      float sum = 0.f;
      #pragma unroll
      for (int j = 0; j < 12; ++j) { l[j] = expf(l[j] - m); sum += l[j]; }
      float inv = 1.0f / sum;
      #pragma unroll
      for (int j = 0; j < 12; ++j) p[j] = l[j] * inv;
    }
    __syncthreads();

    // ---- P3: rewrite as (locx,locy,aw) triplets ----
    {
      const float invWn[3] = {1.f/192.f, 1.f/96.f, 1.f/48.f};
      const float invHn[3] = {1.f/64.f, 1.f/32.f, 1.f/16.f};
      float st[6][3];
      #pragma unroll
      for (int u = 0; u < 6; ++u) {
        int task = u * 512 + t;
        int i = task / 96, s = task % 96;
        int h = s / 12, lp = s % 12, l = lp >> 2, p = lp & 3;
        int oidx = ((h * 3 + l) * 4 + p) * 2;
        float ox = s_oa[i * OAS + oidx] + s_boff[oidx];
        float oy = s_oa[i * OAS + oidx + 1] + s_boff[oidx + 1];
        float aw = s_oa[i * OAS + 192 + h * 12 + lp];
        st[u][0] = s_reff[i * 2] + ox * invWn[l];
        st[u][1] = s_reff[i * 2 + 1] + oy * invHn[l];
        st[u][2] = aw;
      }
      __syncthreads();
      #pragma unroll
      for (int u = 0; u < 6; ++u) {
        int task = u * 512 + t;
        int i = task / 96, s = task % 96;
        float* d = &s_oa[i * OAS + s * 3];
        d[0] = st[u][0]; d[1] = st[u][1]; d[2] = st[u][2];
      }
    }
    __syncthreads();

    // ---- P4: bilinear sampling (bf16 vproj) -> hi/lo into s_qhi/s_qlo ----
    {
      int qsub = t >> 7;
      int cch = t & 127, h = cch >> 4, dh = cch & 15;
      #pragma unroll 1
      for (int g = 0; g < 8; ++g) {
        int i = g * 4 + qsub;
        if (s_vidx[i] >= 0) {
          float acc = 0.f;
          #pragma unroll
          for (int lp = 0; lp < 12; ++lp) {
            const int Wl = (lp < 4) ? 192 : ((lp < 8) ? 96 : 48);
            const int Hl = (lp < 4) ? 64 : ((lp < 8) ? 32 : 16);
            const int Bl = (lp < 4) ? 0 : ((lp < 8) ? 12288 : 15360);
            const float* pd = &s_oa[i * OAS + (h * 12 + lp) * 3];
            float lx = pd[0], ly = pd[1], aw = pd[2];
            float x = lx * (float)Wl - 0.5f, y = ly * (float)Hl - 0.5f;
            float xf = floorf(x), yf = floorf(y);
            float wx = x - xf, wy = y - yf;
            int x0 = (int)xf, y0 = (int)yf;
            const unsigned short* vb = vproj + (size_t)Bl * 128 + h * 16 + dh;
            float sv = 0.f;
            #pragma unroll
            for (int dy2 = 0; dy2 < 2; ++dy2) {
              #pragma unroll
              for (int dx2 = 0; dx2 < 2; ++dx2) {
                int ix = x0 + dx2, iy = y0 + dy2;
                if (ix >= 0 && ix < Wl && iy >= 0 && iy < Hl) {
                  float w = (dx2 ? wx : 1.f - wx) * (dy2 ? wy : 1.f - wy);
                  sv += w * bf2f(vb[(size_t)(iy * Wl + ix) * 128]);
                }
              }
            }
            acc += aw * sv;
          }
          int idxl = i * 128 + (((cch >> 3) ^ (i & 7)) << 3) + (cch & 7);
          unsigned short hi = f2bf(acc);
          s_qhi[idxl] = hi;
          s_qlo[idxl] = f2bf(acc - bf2f(hi));
        }
      }
    }
    __syncthreads();

    // ---- P5: acc @ Wout + identity + bout ----
    if (mflag < 2) {
      int mrow = (wid & 1) * 16;
      int nt0 = (wid >> 1) * 2;
      f32x4 acc2[2];
      #pragma unroll
      for (int r = 0; r < 2; ++r) acc2[r] = (f32x4){0.f,0.f,0.f,0.f};
      int arow = mrow + (lane & 15);
      int asub = lane >> 4;
      #pragma unroll
      for (int kc = 0; kc < 4; ++kc) {
        int slot = kc * 4 + asub;
        int aidx = arow * 128 + ((slot ^ (arow & 7)) << 3);
        short8v ah = *(const short8v*)&s_qhi[aidx];
        short8v al = *(const short8v*)&s_qlo[aidx];
        #pragma unroll
        for (int r = 0; r < 2; ++r) {
          size_t bi = (size_t)(((nt0 + r) * 4 + kc) * 64 + lane) * 8;
          short8v bh = *(const short8v*)&WfragOuth[bi];
          short8v bl = *(const short8v*)&WfragOutl[bi];
          acc2[r] = __builtin_amdgcn_mfma_f32_16x16x32_bf16(ah, bh, acc2[r], 0, 0, 0);
          acc2[r] = __builtin_amdgcn_mfma_f32_16x16x32_bf16(al, bh, acc2[r], 0, 0, 0);
          acc2[r] = __builtin_amdgcn_mfma_f32_16x16x32_bf16(ah, bl, acc2[r], 0, 0, 0);
        }
      }
      #pragma unroll
      for (int r = 0; r < 2; ++r) {
        #pragma unroll
        for (int e = 0; e < 4; ++e) {
          int rr = (mflag == 0) ? ((lane >> 4) * 4 + e) : (lane & 15);
          int cc = (mflag == 0) ? (lane & 15) : ((lane >> 4) * 4 + e);
          int row = mrow + rr;
          int col = (nt0 + r) * 16 + cc;
          int vid = s_vidx[row];
          float idv = (vid >= 0) ? embed[(size_t)vid * 128 + col] : 0.f;
          s_oa[row * OAS + col] = acc2[r][e] + idv + s_bout[col];
        }
      }
    } else {
      int jg = t >> 5, m = t & 31;
      #pragma unroll 1
      for (int jj = 0; jj < 8; ++jj) {
        int j = jg + jj * 16;
        float acc = 0.f;
        #pragma unroll
        for (int slot = 0; slot < 16; ++slot) {
          int aidx = m * 128 + ((slot ^ (m & 7)) << 3);
          const unsigned short* hp = &s_qhi[aidx];
          const unsigned short* lp2 = &s_qlo[aidx];
          const float* wr = &WtOut[j * 128 + slot * 8];
          #pragma unroll
          for (int e2 = 0; e2 < 8; ++e2)
            acc += (bf2f(hp[e2]) + bf2f(lp2[e2])) * wr[e2];
        }
        int vid = s_vidx[m];
        float idv = (vid >= 0) ? embed[(size_t)vid * 128 + j] : 0.f;
        s_oa[m * OAS + j] = acc + idv + s_bout[j];
      }
    }
    __syncthreads();

    // ---- P6: LayerNorm rows ----
    {
      int i = t >> 4, j = t & 15;
      float* rowp = &s_oa[i * OAS];
      float4 a = *(float4*)&rowp[j * 8];
      float4 b = *(float4*)&rowp[j * 8 + 4];
      float vals[8] = {a.x, a.y, a.z, a.w, b.x, b.y, b.z, b.w};
      float sum = 0.f, sq = 0.f;
      #pragma unroll
      for (int e = 0; e < 8; ++e) { sum += vals[e]; sq += vals[e] * vals[e]; }
      #pragma unroll
      for (int m = 1; m < 16; m <<= 1) {
        sum += __shfl_xor(sum, m);
        sq  += __shfl_xor(sq, m);
      }
      float mean = sum * (1.f / 128.f);
      float var = sq * (1.f / 128.f) - mean * mean;
      float rs = rsqrtf(var + 1e-5f);
      #pragma unroll
      for (int e = 0; e < 8; ++e) {
        int c = j * 8 + e;
        rowp[c] = (vals[e] - mean) * rs * s_lng[c] + s_lnb[c];
      }
    }
    __syncthreads();

    // ---- P7: scatter write ----
    #pragma unroll
    for (int rep = 0; rep < 8; ++rep) {
      int idx = rep * 512 + t;
      int c = idx >> 5, i = idx & 31;
      int vid = s_vidx[i];
      if (vid >= 0) out[(size_t)c * V_TOT + vid] = s_oa[i * OAS + c];
    }
    __syncthreads();
  }
}

extern "C" void kernel_launch(void* const* d_in, const int* in_sizes, int n_in,
                              void* d_out, int out_size, void* d_ws, size_t ws_size,
                              hipStream_t stream) {
  const float* embed = (const float*)d_in[0];
  const float* pos   = (const float*)d_in[1];
  const float* refp  = (const float*)d_in[2];
  const float* f0    = (const float*)d_in[3];
  const float* f1    = (const float*)d_in[4];
  const float* f2    = (const float*)d_in[5];
  const float* Wv    = (const float*)d_in[6];
  const float* bv    = (const float*)d_in[7];
  const float* Woff  = (const float*)d_in[8];
  const float* boff  = (const float*)d_in[9];
  const float* Wattn = (const float*)d_in[10];
  const float* battn = (const float*)d_in[11];
  const float* Wout  = (const float*)d_in[12];
  const float* bout  = (const float*)d_in[13];
  const float* lng   = (const float*)d_in[14];
  const float* lnb   = (const float*)d_in[15];
  const int*   volp  = (const int*)d_in[16];
  const unsigned char* fov = (const unsigned char*)d_in[17];
  float* out = (float*)d_out;

  char* ws = (char*)d_ws;
  unsigned short* vproj  = (unsigned short*)(ws + 0);            // 4,128,768
  unsigned char*  pmask  = (unsigned char*)(ws + 4128768);       // 262,144
  unsigned int*   counter= (unsigned int*)(ws + 4390912);        // 128
  int*            pflags = (int*)(ws + 4391040);                 // 128
  unsigned short* foa_hi = (unsigned short*)(ws + 4391168);      // 81,920
  unsigned short* foa_lo = (unsigned short*)(ws + 4473088);      // 81,920
  unsigned short* fout_hi= (unsigned short*)(ws + 4555008);      // 32,768
  unsigned short* fout_lo= (unsigned short*)(ws + 4587776);      // 32,768
  float*          WtOA   = (float*)(ws + 4620544);               // 147,456
  float*          WtOut  = (float*)(ws + 4768000);               // 65,536
  int*            act    = (int*)(ws + 4833536);                 // 1,048,576

  zero_kernel<<<128, 512, 0, stream>>>((unsigned int*)pmask, counter);
  scatter_kernel<<<512, 512, 0, stream>>>(volp, pmask);
  probe_kernel<<<1, 64, 0, stream>>>(fov, pflags);
  vproj_kernel<<<1008, 256, 0, stream>>>(f0, f1, f2, Wv, bv, vproj);
  wfrag_kernel<<<80, 512, 0, stream>>>(Woff, Wattn, Wout, foa_hi, foa_lo,
                                       fout_hi, fout_lo, WtOA, WtOut);
  flags_kernel<<<4096, 256, 0, stream>>>(embed, pmask, fov, pflags, counter, act, out);
  attn_kernel<<<NBLK_ATTN, 512, 0, stream>>>(embed, pos, refp, vproj,
                                             foa_hi, foa_lo, fout_hi, fout_lo,
                                             WtOA, WtOut,
                                             boff, battn, bout, lng, lnb,
                                             act, counter, pflags, out);
}